// Round 13
// baseline (367.822 us; speedup 1.0000x reference)
//
#include <hip/hip_runtime.h>
#include <stdint.h>

#define N_BOX 1024
#define NUM_CLASSES 80
#define MAX_OUT 100
#define KEPT_STRIDE 128
#define WS_POISON 0xAAAAAAAAu

__device__ __forceinline__ void cas64(unsigned long long& a, unsigned long long& b, bool desc) {
    bool sw = desc ? (a < b) : (a > b);
    unsigned long long t = a;
    a = sw ? b : a;
    b = sw ? t : b;
}

// ============ REAL KERNEL: R10 verbatim (best total: 99.8 us) ============
__global__ __launch_bounds__(256) void nms_fused(const float* __restrict__ boxes,
                                                 const float* __restrict__ scores,
                                                 int* __restrict__ keptIdx,
                                                 unsigned int* __restrict__ counts,
                                                 unsigned int* __restrict__ ready,
                                                 int* __restrict__ out) {
    __shared__ float4 sbox[N_BOX];
    __shared__ float sarea[N_BOX];
    __shared__ unsigned long long keys[N_BOX];
    __shared__ float4 kbox[MAX_OUT];
    __shared__ float karea[MAX_OUT];
    __shared__ int scnt[NUM_CLASSES];
    const int c = blockIdx.x;
    const int tid = threadIdx.x;
    const int lane = tid & 63;

    for (int i = tid; i < N_BOX; i += 256) {
        float4 b = reinterpret_cast<const float4*>(boxes)[i];
        sbox[i] = b;
        sarea[i] = (b.z - b.x) * (b.w - b.y);
    }

    const float* sc = scores + (size_t)c * N_BOX;
    float4 s4 = reinterpret_cast<const float4*>(sc)[tid];
    const int i0 = tid * 4;
    unsigned long long K[4];
    K[0] = ((unsigned long long)__float_as_uint(s4.x) << 32) | (unsigned long long)(0xFFFFFFFFu - (unsigned)(i0 + 0));
    K[1] = ((unsigned long long)__float_as_uint(s4.y) << 32) | (unsigned long long)(0xFFFFFFFFu - (unsigned)(i0 + 1));
    K[2] = ((unsigned long long)__float_as_uint(s4.z) << 32) | (unsigned long long)(0xFFFFFFFFu - (unsigned)(i0 + 2));
    K[3] = ((unsigned long long)__float_as_uint(s4.w) << 32) | (unsigned long long)(0xFFFFFFFFu - (unsigned)(i0 + 3));

    auto shfl_pass = [&](int j, bool d) {
        int xl = j >> 2;
        bool mx = (d == ((lane & xl) == 0));
#pragma unroll
        for (int t = 0; t < 4; ++t) {
            unsigned long long p = __shfl_xor(K[t], xl, 64);
            K[t] = mx ? (K[t] >= p ? K[t] : p) : (K[t] <= p ? K[t] : p);
        }
    };
    auto thread_pass = [&](bool d) {
        cas64(K[0], K[2], d); cas64(K[1], K[3], d);
        cas64(K[0], K[1], d); cas64(K[2], K[3], d);
    };
    auto lds_pass = [&](int j, bool d) {
        *reinterpret_cast<ulonglong2*>(&keys[i0])     = make_ulonglong2(K[0], K[1]);
        *reinterpret_cast<ulonglong2*>(&keys[i0 + 2]) = make_ulonglong2(K[2], K[3]);
        __syncthreads();
        int pb = i0 ^ j;
        ulonglong2 p01 = *reinterpret_cast<const ulonglong2*>(&keys[pb]);
        ulonglong2 p23 = *reinterpret_cast<const ulonglong2*>(&keys[pb + 2]);
        unsigned long long P[4] = {p01.x, p01.y, p23.x, p23.y};
        bool mx = (d == ((i0 & j) == 0));
#pragma unroll
        for (int t = 0; t < 4; ++t)
            K[t] = mx ? (K[t] >= P[t] ? K[t] : P[t]) : (K[t] <= P[t] ? K[t] : P[t]);
        __syncthreads();
    };

    cas64(K[0], K[1], true);
    cas64(K[2], K[3], false);
    { bool d = (tid & 1) == 0; thread_pass(d); }
    for (int k = 8; k <= 256; k <<= 1) {
        bool d = (tid & (k >> 2)) == 0;
        for (int j = k >> 1; j >= 4; j >>= 1) shfl_pass(j, d);
        thread_pass(d);
    }
    { bool d = (tid & 128) == 0;
      lds_pass(256, d);
      for (int j = 128; j >= 4; j >>= 1) shfl_pass(j, d);
      thread_pass(d); }
    { lds_pass(512, true); lds_pass(256, true);
      for (int j = 128; j >= 4; j >>= 1) shfl_pass(j, true);
      thread_pass(true); }
    *reinterpret_cast<ulonglong2*>(&keys[i0])     = make_ulonglong2(K[0], K[1]);
    *reinterpret_cast<ulonglong2*>(&keys[i0 + 2]) = make_ulonglong2(K[2], K[3]);
    __syncthreads();

    if (tid < 64) {
        int kept = 0;
        int* outc = keptIdx + c * KEPT_STRIDE;
        for (int base = 0; base < N_BOX && kept < MAX_OUT; base += 64) {
            unsigned long long kk = keys[base + lane];
            unsigned int hi = (unsigned int)(kk >> 32);
            unsigned int o = 0xFFFFFFFFu - (unsigned int)kk;
            bool valid = hi > 0x3F000000u;
            if (__ballot(valid) == 0ull) break;
            float4 mb = sbox[o];
            float ma = sarea[o];
            bool alive = valid;
            for (int j = 0; j < kept; ++j) {
                float4 kb = kbox[j];
                float ih = fminf(kb.z, mb.z) - fmaxf(kb.x, mb.x); ih = fmaxf(ih, 0.0f);
                float iw = fminf(kb.w, mb.w) - fmaxf(kb.y, mb.y); iw = fmaxf(iw, 0.0f);
                float inter = ih * iw;
                float uni = karea[j] + ma - inter;
                alive = alive && !((inter / uni) > 0.5f);
            }
            unsigned long long m = __ballot(alive);
            if (m == 0ull) continue;
            unsigned long long row = 0ull;
#pragma unroll 8
            for (int j = 0; j < 64; ++j) {
                unsigned int oj = (unsigned int)__shfl((int)o, j);
                float4 bj = sbox[oj];
                float aj = sarea[oj];
                float ih = fminf(bj.z, mb.z) - fmaxf(bj.x, mb.x); ih = fmaxf(ih, 0.0f);
                float iw = fminf(bj.w, mb.w) - fmaxf(bj.y, mb.y); iw = fmaxf(iw, 0.0f);
                float inter = ih * iw;
                float uni = aj + ma - inter;
                if ((inter / uni) > 0.5f) row |= 1ull << j;
            }
            unsigned long long Km = 0ull;
            int kept0 = kept;
            while (m != 0ull && kept < MAX_OUT) {
                int f = __builtin_ctzll(m);
                Km |= 1ull << f;
                ++kept;
                unsigned int rlo = (unsigned int)__builtin_amdgcn_readlane((int)(unsigned int)row, f);
                unsigned int rhi = (unsigned int)__builtin_amdgcn_readlane((int)(unsigned int)(row >> 32), f);
                unsigned long long rowf = ((unsigned long long)rhi << 32) | rlo;
                m &= ~rowf;
            }
            if ((Km >> lane) & 1ull) {
                int pos = kept0 + __popcll(Km & ((1ull << lane) - 1ull));
                outc[pos] = (int)o;
                kbox[pos] = mb;
                karea[pos] = ma;
            }
        }
        if (lane == 0) {
            __hip_atomic_store(&counts[c], (unsigned int)kept,
                               __ATOMIC_RELEASE, __HIP_MEMORY_SCOPE_SYSTEM);
            __hip_atomic_fetch_add(ready, 1u,
                                   __ATOMIC_RELEASE, __HIP_MEMORY_SCOPE_SYSTEM);
        }
    }

    if (c != 0) return;

    if (tid == 64) {
        const unsigned int target = WS_POISON + (unsigned int)NUM_CLASSES;
        unsigned int v;
        do {
            v = __hip_atomic_fetch_add(ready, 0u, __ATOMIC_ACQUIRE, __HIP_MEMORY_SCOPE_SYSTEM);
        } while (v != target);
    } else if (tid >= 144) {
        int4* o4 = reinterpret_cast<int4*>(out);
        for (int i = tid - 144; i < (NUM_CLASSES * MAX_OUT * 3) / 4; i += 112)
            o4[i] = make_int4(0, 0, 0, 0);
    }
    __syncthreads();

    if (tid < NUM_CLASSES)
        scnt[tid] = (int)__hip_atomic_load(&counts[tid], __ATOMIC_RELAXED,
                                           __HIP_MEMORY_SCOPE_SYSTEM);
    __syncthreads();

    for (int d = 1; d < NUM_CLASSES; d <<= 1) {
        int v = 0;
        if (tid < NUM_CLASSES) {
            v = scnt[tid];
            if (tid >= d) v += scnt[tid - d];
        }
        __syncthreads();
        if (tid < NUM_CLASSES) scnt[tid] = v;
        __syncthreads();
    }

    for (int idx = tid; idx < NUM_CLASSES * MAX_OUT; idx += 256) {
        int c2 = idx / MAX_OUT;
        int r = idx - c2 * MAX_OUT;
        int excl = (c2 == 0) ? 0 : scnt[c2 - 1];
        if (r < scnt[c2] - excl) {
            int o = excl + r;
            out[o * 3 + 0] = 0;
            out[o * 3 + 1] = c2;
            out[o * 3 + 2] = keptIdx[c2 * KEPT_STRIDE + r];
        }
    }
}

// ============ PROBES (write only to scratch; amplify each phase x8) ============

// P1: staging x8.
__global__ __launch_bounds__(256) void probe_stage8(const float* __restrict__ boxes,
                                                    float* __restrict__ scratch) {
    __shared__ float4 sbox[N_BOX];
    __shared__ float sarea[N_BOX];
    const int tid = threadIdx.x;
    float acc = 0.0f;
    for (int it = 0; it < 8; ++it) {
        for (int i = tid; i < N_BOX; i += 256) {
            float4 b = reinterpret_cast<const float4*>(boxes)[i];
            sbox[i] = b;
            sarea[i] = (b.z - b.x) * (b.w - b.y);
        }
        __syncthreads();
        acc += sarea[(tid + it) & (N_BOX - 1)] + sbox[(tid * 7 + it) & (N_BOX - 1)].x;
        __syncthreads();
    }
    scratch[blockIdx.x * 256 + tid] = acc;
}

// P2: staging + (key build + full hybrid sort) x8.
__global__ __launch_bounds__(256) void probe_sort8(const float* __restrict__ scores,
                                                   unsigned long long* __restrict__ pkeys) {
    __shared__ unsigned long long keys[N_BOX];
    const int c = blockIdx.x;
    const int tid = threadIdx.x;
    const int lane = tid & 63;
    const float* sc = scores + (size_t)c * N_BOX;
    float4 s4 = reinterpret_cast<const float4*>(sc)[tid];
    const int i0 = tid * 4;

    for (int it = 0; it < 8; ++it) {
        unsigned long long K[4];
        // fold iteration into the index bits (keeps order semantics, prevents elision)
        unsigned int salt = (unsigned int)it;
        K[0] = ((unsigned long long)__float_as_uint(s4.x) << 32) | (unsigned long long)(0xFFFFFFFFu - (unsigned)(i0 + 0) - salt);
        K[1] = ((unsigned long long)__float_as_uint(s4.y) << 32) | (unsigned long long)(0xFFFFFFFFu - (unsigned)(i0 + 1) - salt);
        K[2] = ((unsigned long long)__float_as_uint(s4.z) << 32) | (unsigned long long)(0xFFFFFFFFu - (unsigned)(i0 + 2) - salt);
        K[3] = ((unsigned long long)__float_as_uint(s4.w) << 32) | (unsigned long long)(0xFFFFFFFFu - (unsigned)(i0 + 3) - salt);

        auto shfl_pass = [&](int j, bool d) {
            int xl = j >> 2;
            bool mx = (d == ((lane & xl) == 0));
#pragma unroll
            for (int t = 0; t < 4; ++t) {
                unsigned long long p = __shfl_xor(K[t], xl, 64);
                K[t] = mx ? (K[t] >= p ? K[t] : p) : (K[t] <= p ? K[t] : p);
            }
        };
        auto thread_pass = [&](bool d) {
            cas64(K[0], K[2], d); cas64(K[1], K[3], d);
            cas64(K[0], K[1], d); cas64(K[2], K[3], d);
        };
        auto lds_pass = [&](int j, bool d) {
            *reinterpret_cast<ulonglong2*>(&keys[i0])     = make_ulonglong2(K[0], K[1]);
            *reinterpret_cast<ulonglong2*>(&keys[i0 + 2]) = make_ulonglong2(K[2], K[3]);
            __syncthreads();
            int pb = i0 ^ j;
            ulonglong2 p01 = *reinterpret_cast<const ulonglong2*>(&keys[pb]);
            ulonglong2 p23 = *reinterpret_cast<const ulonglong2*>(&keys[pb + 2]);
            unsigned long long P[4] = {p01.x, p01.y, p23.x, p23.y};
            bool mx = (d == ((i0 & j) == 0));
#pragma unroll
            for (int t = 0; t < 4; ++t)
                K[t] = mx ? (K[t] >= P[t] ? K[t] : P[t]) : (K[t] <= P[t] ? K[t] : P[t]);
            __syncthreads();
        };

        cas64(K[0], K[1], true);
        cas64(K[2], K[3], false);
        { bool d = (tid & 1) == 0; thread_pass(d); }
        for (int k = 8; k <= 256; k <<= 1) {
            bool d = (tid & (k >> 2)) == 0;
            for (int j = k >> 1; j >= 4; j >>= 1) shfl_pass(j, d);
            thread_pass(d);
        }
        { bool d = (tid & 128) == 0;
          lds_pass(256, d);
          for (int j = 128; j >= 4; j >>= 1) shfl_pass(j, d);
          thread_pass(d); }
        { lds_pass(512, true); lds_pass(256, true);
          for (int j = 128; j >= 4; j >>= 1) shfl_pass(j, true);
          thread_pass(true); }

        unsigned long long* gk = pkeys + (size_t)c * N_BOX;
        *reinterpret_cast<ulonglong2*>(&gk[i0])     = make_ulonglong2(K[0], K[1]);
        *reinterpret_cast<ulonglong2*>(&gk[i0 + 2]) = make_ulonglong2(K[2], K[3]);
        __syncthreads();
    }
}

// P3: staging + sort x1 + greedy x8.
__global__ __launch_bounds__(256) void probe_greedy8(const float* __restrict__ boxes,
                                                     const float* __restrict__ scores,
                                                     int* __restrict__ pkept,
                                                     unsigned int* __restrict__ pcounts) {
    __shared__ float4 sbox[N_BOX];
    __shared__ float sarea[N_BOX];
    __shared__ unsigned long long keys[N_BOX];
    __shared__ float4 kbox[MAX_OUT];
    __shared__ float karea[MAX_OUT];
    const int c = blockIdx.x;
    const int tid = threadIdx.x;
    const int lane = tid & 63;

    for (int i = tid; i < N_BOX; i += 256) {
        float4 b = reinterpret_cast<const float4*>(boxes)[i];
        sbox[i] = b;
        sarea[i] = (b.z - b.x) * (b.w - b.y);
    }
    const float* sc = scores + (size_t)c * N_BOX;
    float4 s4 = reinterpret_cast<const float4*>(sc)[tid];
    const int i0 = tid * 4;
    unsigned long long K[4];
    K[0] = ((unsigned long long)__float_as_uint(s4.x) << 32) | (unsigned long long)(0xFFFFFFFFu - (unsigned)(i0 + 0));
    K[1] = ((unsigned long long)__float_as_uint(s4.y) << 32) | (unsigned long long)(0xFFFFFFFFu - (unsigned)(i0 + 1));
    K[2] = ((unsigned long long)__float_as_uint(s4.z) << 32) | (unsigned long long)(0xFFFFFFFFu - (unsigned)(i0 + 2));
    K[3] = ((unsigned long long)__float_as_uint(s4.w) << 32) | (unsigned long long)(0xFFFFFFFFu - (unsigned)(i0 + 3));
    auto shfl_pass = [&](int j, bool d) {
        int xl = j >> 2;
        bool mx = (d == ((lane & xl) == 0));
#pragma unroll
        for (int t = 0; t < 4; ++t) {
            unsigned long long p = __shfl_xor(K[t], xl, 64);
            K[t] = mx ? (K[t] >= p ? K[t] : p) : (K[t] <= p ? K[t] : p);
        }
    };
    auto thread_pass = [&](bool d) {
        cas64(K[0], K[2], d); cas64(K[1], K[3], d);
        cas64(K[0], K[1], d); cas64(K[2], K[3], d);
    };
    auto lds_pass = [&](int j, bool d) {
        *reinterpret_cast<ulonglong2*>(&keys[i0])     = make_ulonglong2(K[0], K[1]);
        *reinterpret_cast<ulonglong2*>(&keys[i0 + 2]) = make_ulonglong2(K[2], K[3]);
        __syncthreads();
        int pb = i0 ^ j;
        ulonglong2 p01 = *reinterpret_cast<const ulonglong2*>(&keys[pb]);
        ulonglong2 p23 = *reinterpret_cast<const ulonglong2*>(&keys[pb + 2]);
        unsigned long long P[4] = {p01.x, p01.y, p23.x, p23.y};
        bool mx = (d == ((i0 & j) == 0));
#pragma unroll
        for (int t = 0; t < 4; ++t)
            K[t] = mx ? (K[t] >= P[t] ? K[t] : P[t]) : (K[t] <= P[t] ? K[t] : P[t]);
        __syncthreads();
    };
    cas64(K[0], K[1], true);
    cas64(K[2], K[3], false);
    { bool d = (tid & 1) == 0; thread_pass(d); }
    for (int k = 8; k <= 256; k <<= 1) {
        bool d = (tid & (k >> 2)) == 0;
        for (int j = k >> 1; j >= 4; j >>= 1) shfl_pass(j, d);
        thread_pass(d);
    }
    { bool d = (tid & 128) == 0;
      lds_pass(256, d);
      for (int j = 128; j >= 4; j >>= 1) shfl_pass(j, d);
      thread_pass(d); }
    { lds_pass(512, true); lds_pass(256, true);
      for (int j = 128; j >= 4; j >>= 1) shfl_pass(j, true);
      thread_pass(true); }
    *reinterpret_cast<ulonglong2*>(&keys[i0])     = make_ulonglong2(K[0], K[1]);
    *reinterpret_cast<ulonglong2*>(&keys[i0 + 2]) = make_ulonglong2(K[2], K[3]);
    __syncthreads();

    if (tid < 64) {
        int keptTot = 0;
        for (int it = 0; it < 8; ++it) {
            int kept = 0;
            int* outc = pkept + c * KEPT_STRIDE;
            for (int base = 0; base < N_BOX && kept < MAX_OUT; base += 64) {
                unsigned long long kk = keys[base + lane];
                unsigned int hi = (unsigned int)(kk >> 32);
                unsigned int o = 0xFFFFFFFFu - (unsigned int)kk;
                bool valid = hi > (0x3F000000u + (unsigned)it * 0u);
                if (__ballot(valid) == 0ull) break;
                float4 mb = sbox[o];
                float ma = sarea[o];
                bool alive = valid;
                for (int j = 0; j < kept; ++j) {
                    float4 kb = kbox[j];
                    float ih = fminf(kb.z, mb.z) - fmaxf(kb.x, mb.x); ih = fmaxf(ih, 0.0f);
                    float iw = fminf(kb.w, mb.w) - fmaxf(kb.y, mb.y); iw = fmaxf(iw, 0.0f);
                    float inter = ih * iw;
                    float uni = karea[j] + ma - inter;
                    alive = alive && !((inter / uni) > 0.5f);
                }
                unsigned long long m = __ballot(alive);
                if (m == 0ull) continue;
                unsigned long long row = 0ull;
#pragma unroll 8
                for (int j = 0; j < 64; ++j) {
                    unsigned int oj = (unsigned int)__shfl((int)o, j);
                    float4 bj = sbox[oj];
                    float aj = sarea[oj];
                    float ih = fminf(bj.z, mb.z) - fmaxf(bj.x, mb.x); ih = fmaxf(ih, 0.0f);
                    float iw = fminf(bj.w, mb.w) - fmaxf(bj.y, mb.y); iw = fmaxf(iw, 0.0f);
                    float inter = ih * iw;
                    float uni = aj + ma - inter;
                    if ((inter / uni) > 0.5f) row |= 1ull << j;
                }
                unsigned long long Km = 0ull;
                int kept0 = kept;
                while (m != 0ull && kept < MAX_OUT) {
                    int f = __builtin_ctzll(m);
                    Km |= 1ull << f;
                    ++kept;
                    unsigned int rlo = (unsigned int)__builtin_amdgcn_readlane((int)(unsigned int)row, f);
                    unsigned int rhi = (unsigned int)__builtin_amdgcn_readlane((int)(unsigned int)(row >> 32), f);
                    unsigned long long rowf = ((unsigned long long)rhi << 32) | rlo;
                    m &= ~rowf;
                }
                if ((Km >> lane) & 1ull) {
                    int pos = kept0 + __popcll(Km & ((1ull << lane) - 1ull));
                    outc[pos] = (int)o;
                    kbox[pos] = mb;
                    karea[pos] = ma;
                }
            }
            keptTot += kept;
        }
        if (lane == 0) pcounts[c] = (unsigned int)keptTot;
    }
}

extern "C" void kernel_launch(void* const* d_in, const int* in_sizes, int n_in,
                              void* d_out, int out_size, void* d_ws, size_t ws_size,
                              hipStream_t stream) {
    const float* boxes = (const float*)d_in[0];
    const float* scores = (const float*)d_in[1];
    int* out = (int*)d_out;

    char* ws = (char*)d_ws;
    int* keptIdx = (int*)ws;                                        // 80*128 ints
    unsigned int* counts = (unsigned int*)(keptIdx + NUM_CLASSES * KEPT_STRIDE);
    unsigned int* ready = counts + 128;
    // probe scratch, far from the real region
    float* pscr = (float*)(ws + (1 << 20));                         // 80*256 floats
    unsigned long long* pkeys = (unsigned long long*)(ws + (2 << 20));  // 640 KB
    int* pkept = (int*)(ws + (3 << 20));
    unsigned int* pcounts = (unsigned int*)(ws + (3 << 20) + 65536);

    nms_fused<<<NUM_CLASSES, 256, 0, stream>>>(boxes, scores, keptIdx, counts, ready, out);
    probe_stage8<<<NUM_CLASSES, 256, 0, stream>>>(boxes, pscr);
    probe_sort8<<<NUM_CLASSES, 256, 0, stream>>>(scores, pkeys);
    probe_greedy8<<<NUM_CLASSES, 256, 0, stream>>>(boxes, scores, pkept, pcounts);
}

// Round 14
// 89.360 us; speedup vs baseline: 4.1162x; 4.1162x over previous
//
#include <hip/hip_runtime.h>
#include <stdint.h>

#define N_BOX 1024
#define NUM_CLASSES 80
#define MAX_OUT 100
#define KEPT_STRIDE 128  // ints per class (512 B)
#define WS_POISON 0xAAAAAAAAu

__device__ __forceinline__ void cas64(unsigned long long& a, unsigned long long& b, bool desc) {
    bool sw = desc ? (a < b) : (a > b);
    unsigned long long t = a;
    a = sw ? b : a;
    b = sw ? t : b;
}

// Single fused dispatch, 80 blocks (one class each). R10 structure, but the greedy's
// two heavy loops (cross-window kept-test, in-window 64x64 IoU matrix) are computed
// ON-DEMAND PER WINDOW by ALL 4 WAVES (R13 probes: greedy was 25.6us of the kernel,
// single-wave latency-exposed; sort+staging are only ~3us). Wave 0 keeps the cheap
// serial resolution. Publish/poll/epilogue identical to R10 (proven).
__global__ __launch_bounds__(256) void nms_fused(const float* __restrict__ boxes,
                                                 const float* __restrict__ scores,
                                                 int* __restrict__ keptIdx,
                                                 unsigned int* __restrict__ counts,
                                                 unsigned int* __restrict__ ready,
                                                 int* __restrict__ out) {
    __shared__ float4 sbox[N_BOX];              // 16 KB
    __shared__ float sarea[N_BOX];              // 4 KB
    __shared__ unsigned long long keys[N_BOX];  // 8 KB
    __shared__ float4 kbox[MAX_OUT];            // kept boxes
    __shared__ float karea[MAX_OUT];
    __shared__ unsigned long long supp[4];      // per-wave suppressed ballots
    __shared__ unsigned long long wmp[4][64];   // per-wave 16-col row chunks (2 KB)
    __shared__ int keptLDS;
    __shared__ int scnt[NUM_CLASSES];
    const int c = blockIdx.x;
    const int tid = threadIdx.x;
    const int lane = tid & 63;
    const int wv = tid >> 6;

    for (int i = tid; i < N_BOX; i += 256) {
        float4 b = reinterpret_cast<const float4*>(boxes)[i];
        sbox[i] = b;
        sarea[i] = (b.z - b.x) * (b.w - b.y);
    }

    // Keys: (score_bits<<32) | (0xFFFFFFFF - idx); descending == stable argsort(-scores).
    const float* sc = scores + (size_t)c * N_BOX;
    float4 s4 = reinterpret_cast<const float4*>(sc)[tid];
    const int i0 = tid * 4;
    unsigned long long K[4];
    K[0] = ((unsigned long long)__float_as_uint(s4.x) << 32) | (unsigned long long)(0xFFFFFFFFu - (unsigned)(i0 + 0));
    K[1] = ((unsigned long long)__float_as_uint(s4.y) << 32) | (unsigned long long)(0xFFFFFFFFu - (unsigned)(i0 + 1));
    K[2] = ((unsigned long long)__float_as_uint(s4.z) << 32) | (unsigned long long)(0xFFFFFFFFu - (unsigned)(i0 + 2));
    K[3] = ((unsigned long long)__float_as_uint(s4.w) << 32) | (unsigned long long)(0xFFFFFFFFu - (unsigned)(i0 + 3));

    auto shfl_pass = [&](int j, bool d) {
        int xl = j >> 2;
        bool mx = (d == ((lane & xl) == 0));
#pragma unroll
        for (int t = 0; t < 4; ++t) {
            unsigned long long p = __shfl_xor(K[t], xl, 64);
            K[t] = mx ? (K[t] >= p ? K[t] : p) : (K[t] <= p ? K[t] : p);
        }
    };
    auto thread_pass = [&](bool d) {
        cas64(K[0], K[2], d); cas64(K[1], K[3], d);
        cas64(K[0], K[1], d); cas64(K[2], K[3], d);
    };
    auto lds_pass = [&](int j, bool d) {
        *reinterpret_cast<ulonglong2*>(&keys[i0])     = make_ulonglong2(K[0], K[1]);
        *reinterpret_cast<ulonglong2*>(&keys[i0 + 2]) = make_ulonglong2(K[2], K[3]);
        __syncthreads();
        int pb = i0 ^ j;
        ulonglong2 p01 = *reinterpret_cast<const ulonglong2*>(&keys[pb]);
        ulonglong2 p23 = *reinterpret_cast<const ulonglong2*>(&keys[pb + 2]);
        unsigned long long P[4] = {p01.x, p01.y, p23.x, p23.y};
        bool mx = (d == ((i0 & j) == 0));
#pragma unroll
        for (int t = 0; t < 4; ++t)
            K[t] = mx ? (K[t] >= P[t] ? K[t] : P[t]) : (K[t] <= P[t] ? K[t] : P[t]);
        __syncthreads();
    };

    cas64(K[0], K[1], true);
    cas64(K[2], K[3], false);
    { bool d = (tid & 1) == 0; thread_pass(d); }
    for (int k = 8; k <= 256; k <<= 1) {
        bool d = (tid & (k >> 2)) == 0;
        for (int j = k >> 1; j >= 4; j >>= 1) shfl_pass(j, d);
        thread_pass(d);
    }
    { bool d = (tid & 128) == 0;
      lds_pass(256, d);
      for (int j = 128; j >= 4; j >>= 1) shfl_pass(j, d);
      thread_pass(d); }
    { lds_pass(512, true); lds_pass(256, true);
      for (int j = 128; j >= 4; j >>= 1) shfl_pass(j, true);
      thread_pass(true); }
    *reinterpret_cast<ulonglong2*>(&keys[i0])     = make_ulonglong2(K[0], K[1]);
    *reinterpret_cast<ulonglong2*>(&keys[i0 + 2]) = make_ulonglong2(K[2], K[3]);
    if (tid == 0) keptLDS = 0;
    __syncthreads();  // keys + staging + keptLDS ready

    // --- Greedy NMS: all 4 waves cooperate per window; wave 0 resolves serially ---
    {
        int kept = 0;
        int* outc = keptIdx + c * KEPT_STRIDE;
        for (int base = 0; base < N_BOX && kept < MAX_OUT; base += 64) {
            // Every wave reads the SAME window slots -> identical per-wave values.
            unsigned long long kk = keys[base + lane];
            unsigned int hi = (unsigned int)(kk >> 32);
            unsigned int o = 0xFFFFFFFFu - (unsigned int)kk;
            bool valid = hi > 0x3F000000u;               // score > 0.5f
            unsigned long long vb = __ballot(valid);      // uniform across waves
            if (vb == 0ull) break;                        // uniform exit
            float4 mb = sbox[o];
            float ma = sarea[o];
            // Phase 1 (all waves): candidate `lane` vs kept j in {wv, wv+4, ...}.
            bool sup_part = false;
            for (int j = wv; j < kept; j += 4) {
                float4 kb = kbox[j];
                float ih = fminf(kb.z, mb.z) - fmaxf(kb.x, mb.x); ih = fmaxf(ih, 0.0f);
                float iw = fminf(kb.w, mb.w) - fmaxf(kb.y, mb.y); iw = fmaxf(iw, 0.0f);
                float inter = ih * iw;
                float uni = karea[j] + ma - inter;       // ref op order
                sup_part = sup_part || ((inter / uni) > 0.5f);
            }
            unsigned long long sb = __ballot(sup_part);
            if (lane == 0) supp[wv] = sb;
            __syncthreads();
            unsigned long long m = vb & ~(supp[0] | supp[1] | supp[2] | supp[3]);
            bool doM = (m != 0ull);                      // uniform across all threads
            // Phase 2 (all waves): row chunk for candidate `lane`, cols [16wv,16wv+16).
            if (doM) {
                unsigned long long chunk = 0ull;
#pragma unroll
                for (int jj = 0; jj < 16; ++jj) {
                    int j = (wv << 4) + jj;
                    unsigned long long kj = keys[base + j];        // uniform LDS read
                    unsigned int oj = 0xFFFFFFFFu - (unsigned int)kj;
                    float4 bj = sbox[oj];
                    float aj = sarea[oj];
                    float ih = fminf(bj.z, mb.z) - fmaxf(bj.x, mb.x); ih = fmaxf(ih, 0.0f);
                    float iw = fminf(bj.w, mb.w) - fmaxf(bj.y, mb.y); iw = fmaxf(iw, 0.0f);
                    float inter = ih * iw;
                    float uni = aj + ma - inter;
                    if ((inter / uni) > 0.5f) chunk |= 1ull << jj;
                }
                wmp[wv][lane] = chunk << (wv << 4);
            }
            __syncthreads();
            // Phase 3 (wave 0 only): serial resolution + parallel append.
            if (doM && tid < 64) {
                unsigned long long row = wmp[0][lane] | wmp[1][lane] | wmp[2][lane] | wmp[3][lane];
                unsigned long long Km = 0ull;
                int kept0 = kept;
                while (m != 0ull && kept < MAX_OUT) {
                    int f = __builtin_ctzll(m);
                    Km |= 1ull << f;
                    ++kept;
                    unsigned int rlo = (unsigned int)__builtin_amdgcn_readlane((int)(unsigned int)row, f);
                    unsigned int rhi = (unsigned int)__builtin_amdgcn_readlane((int)(unsigned int)(row >> 32), f);
                    unsigned long long rowf = ((unsigned long long)rhi << 32) | rlo;
                    m &= ~rowf;                          // clears f (self-bit) + suppressed
                }
                if ((Km >> lane) & 1ull) {
                    int pos = kept0 + __popcll(Km & ((1ull << lane) - 1ull));
                    outc[pos] = (int)o;
                    kbox[pos] = mb;
                    karea[pos] = ma;
                }
                if (lane == 0) keptLDS = kept;
            }
            __syncthreads();  // kept/kbox/karea visible to all waves
            kept = keptLDS;
        }
        if (tid == 0) {
            __hip_atomic_store(&counts[c], (unsigned int)kept,
                               __ATOMIC_RELEASE, __HIP_MEMORY_SCOPE_SYSTEM);
            __hip_atomic_fetch_add(ready, 1u,
                                   __ATOMIC_RELEASE, __HIP_MEMORY_SCOPE_SYSTEM);
        }
    }

    if (c != 0) return;  // blocks 1..79 done

    // --- Block 0 epilogue (R9/R10-proven) ---
    if (tid == 64) {
        const unsigned int target = WS_POISON + (unsigned int)NUM_CLASSES;
        unsigned int v;
        do {
            v = __hip_atomic_fetch_add(ready, 0u, __ATOMIC_ACQUIRE, __HIP_MEMORY_SCOPE_SYSTEM);
        } while (v != target);
    } else if (tid >= 144) {
        int4* o4 = reinterpret_cast<int4*>(out);
        for (int i = tid - 144; i < (NUM_CLASSES * MAX_OUT * 3) / 4; i += 112)
            o4[i] = make_int4(0, 0, 0, 0);
    }
    __syncthreads();

    if (tid < NUM_CLASSES)
        scnt[tid] = (int)__hip_atomic_load(&counts[tid], __ATOMIC_RELAXED,
                                           __HIP_MEMORY_SCOPE_SYSTEM);
    __syncthreads();

    for (int d = 1; d < NUM_CLASSES; d <<= 1) {
        int v = 0;
        if (tid < NUM_CLASSES) {
            v = scnt[tid];
            if (tid >= d) v += scnt[tid - d];
        }
        __syncthreads();
        if (tid < NUM_CLASSES) scnt[tid] = v;
        __syncthreads();
    }

    for (int idx = tid; idx < NUM_CLASSES * MAX_OUT; idx += 256) {
        int c2 = idx / MAX_OUT;
        int r = idx - c2 * MAX_OUT;
        int excl = (c2 == 0) ? 0 : scnt[c2 - 1];
        if (r < scnt[c2] - excl) {
            int o = excl + r;
            out[o * 3 + 0] = 0;  // B == 1
            out[o * 3 + 1] = c2;
            out[o * 3 + 2] = keptIdx[c2 * KEPT_STRIDE + r];
        }
    }
}

extern "C" void kernel_launch(void* const* d_in, const int* in_sizes, int n_in,
                              void* d_out, int out_size, void* d_ws, size_t ws_size,
                              hipStream_t stream) {
    const float* boxes = (const float*)d_in[0];   // (1, 1024, 4) f32
    const float* scores = (const float*)d_in[1];  // (1, 80, 1024) f32
    int* out = (int*)d_out;                        // (8000, 3) int32

    int* keptIdx = (int*)d_ws;                                     // 80*128 ints
    unsigned int* counts = (unsigned int*)(keptIdx + NUM_CLASSES * KEPT_STRIDE);
    unsigned int* ready = counts + 128;            // own 512B-aligned region

    nms_fused<<<NUM_CLASSES, 256, 0, stream>>>(boxes, scores, keptIdx, counts, ready, out);
}

// Round 15
// 88.831 us; speedup vs baseline: 4.1407x; 1.0059x over previous
//
#include <hip/hip_runtime.h>
#include <stdint.h>

#define N_BOX 1024
#define NUM_CLASSES 80
#define MAX_OUT 100
#define KEPT_STRIDE 128  // ints per class (512 B)
#define WS_POISON 0xAAAAAAAAu

__device__ __forceinline__ void cas64(unsigned long long& a, unsigned long long& b, bool desc) {
    bool sw = desc ? (a < b) : (a > b);
    unsigned long long t = a;
    a = sw ? b : a;
    b = sw ? t : b;
}

// Single fused dispatch, 80 blocks (one class each). R14 structure (4-wave cooperative
// greedy) with a LAST-FINISHER epilogue: no polling anywhere — each block fetch_adds a
// ready counter after publishing its count; the block that observes prev==poison+79 is
// the last finisher and runs the compaction itself. Removes block-0's spin-RMW (which
// contended with all 79 publishes on the coherence point) and the block-0 asymmetry.
__global__ __launch_bounds__(256) void nms_fused(const float* __restrict__ boxes,
                                                 const float* __restrict__ scores,
                                                 int* __restrict__ keptIdx,
                                                 unsigned int* __restrict__ counts,
                                                 unsigned int* __restrict__ ready,
                                                 int* __restrict__ out) {
    __shared__ float4 sbox[N_BOX];              // 16 KB
    __shared__ float sarea[N_BOX];              // 4 KB
    __shared__ unsigned long long keys[N_BOX];  // 8 KB
    __shared__ float4 kbox[MAX_OUT];            // kept boxes
    __shared__ float karea[MAX_OUT];
    __shared__ unsigned long long supp[4];      // per-wave suppressed ballots
    __shared__ unsigned long long wmp[4][64];   // per-wave 16-col row chunks (2 KB)
    __shared__ int keptLDS;
    __shared__ int lastFlag;
    __shared__ int scnt[NUM_CLASSES];
    const int c = blockIdx.x;
    const int tid = threadIdx.x;
    const int lane = tid & 63;
    const int wv = tid >> 6;

    for (int i = tid; i < N_BOX; i += 256) {
        float4 b = reinterpret_cast<const float4*>(boxes)[i];
        sbox[i] = b;
        sarea[i] = (b.z - b.x) * (b.w - b.y);
    }

    // Keys: (score_bits<<32) | (0xFFFFFFFF - idx); descending == stable argsort(-scores).
    const float* sc = scores + (size_t)c * N_BOX;
    float4 s4 = reinterpret_cast<const float4*>(sc)[tid];
    const int i0 = tid * 4;
    unsigned long long K[4];
    K[0] = ((unsigned long long)__float_as_uint(s4.x) << 32) | (unsigned long long)(0xFFFFFFFFu - (unsigned)(i0 + 0));
    K[1] = ((unsigned long long)__float_as_uint(s4.y) << 32) | (unsigned long long)(0xFFFFFFFFu - (unsigned)(i0 + 1));
    K[2] = ((unsigned long long)__float_as_uint(s4.z) << 32) | (unsigned long long)(0xFFFFFFFFu - (unsigned)(i0 + 2));
    K[3] = ((unsigned long long)__float_as_uint(s4.w) << 32) | (unsigned long long)(0xFFFFFFFFu - (unsigned)(i0 + 3));

    auto shfl_pass = [&](int j, bool d) {
        int xl = j >> 2;
        bool mx = (d == ((lane & xl) == 0));
#pragma unroll
        for (int t = 0; t < 4; ++t) {
            unsigned long long p = __shfl_xor(K[t], xl, 64);
            K[t] = mx ? (K[t] >= p ? K[t] : p) : (K[t] <= p ? K[t] : p);
        }
    };
    auto thread_pass = [&](bool d) {
        cas64(K[0], K[2], d); cas64(K[1], K[3], d);
        cas64(K[0], K[1], d); cas64(K[2], K[3], d);
    };
    auto lds_pass = [&](int j, bool d) {
        *reinterpret_cast<ulonglong2*>(&keys[i0])     = make_ulonglong2(K[0], K[1]);
        *reinterpret_cast<ulonglong2*>(&keys[i0 + 2]) = make_ulonglong2(K[2], K[3]);
        __syncthreads();
        int pb = i0 ^ j;
        ulonglong2 p01 = *reinterpret_cast<const ulonglong2*>(&keys[pb]);
        ulonglong2 p23 = *reinterpret_cast<const ulonglong2*>(&keys[pb + 2]);
        unsigned long long P[4] = {p01.x, p01.y, p23.x, p23.y};
        bool mx = (d == ((i0 & j) == 0));
#pragma unroll
        for (int t = 0; t < 4; ++t)
            K[t] = mx ? (K[t] >= P[t] ? K[t] : P[t]) : (K[t] <= P[t] ? K[t] : P[t]);
        __syncthreads();
    };

    cas64(K[0], K[1], true);
    cas64(K[2], K[3], false);
    { bool d = (tid & 1) == 0; thread_pass(d); }
    for (int k = 8; k <= 256; k <<= 1) {
        bool d = (tid & (k >> 2)) == 0;
        for (int j = k >> 1; j >= 4; j >>= 1) shfl_pass(j, d);
        thread_pass(d);
    }
    { bool d = (tid & 128) == 0;
      lds_pass(256, d);
      for (int j = 128; j >= 4; j >>= 1) shfl_pass(j, d);
      thread_pass(d); }
    { lds_pass(512, true); lds_pass(256, true);
      for (int j = 128; j >= 4; j >>= 1) shfl_pass(j, true);
      thread_pass(true); }
    *reinterpret_cast<ulonglong2*>(&keys[i0])     = make_ulonglong2(K[0], K[1]);
    *reinterpret_cast<ulonglong2*>(&keys[i0 + 2]) = make_ulonglong2(K[2], K[3]);
    if (tid == 0) keptLDS = 0;
    __syncthreads();  // keys + staging + keptLDS ready

    // --- Greedy NMS: all 4 waves cooperate per window; wave 0 resolves serially ---
    int kept = 0;
    {
        int* outc = keptIdx + c * KEPT_STRIDE;
        for (int base = 0; base < N_BOX && kept < MAX_OUT; base += 64) {
            // Every wave reads the SAME window slots -> identical per-wave values.
            unsigned long long kk = keys[base + lane];
            unsigned int hi = (unsigned int)(kk >> 32);
            unsigned int o = 0xFFFFFFFFu - (unsigned int)kk;
            bool valid = hi > 0x3F000000u;               // score > 0.5f
            unsigned long long vb = __ballot(valid);      // uniform across waves
            if (vb == 0ull) break;                        // uniform exit
            float4 mb = sbox[o];
            float ma = sarea[o];
            // Phase 1 (all waves): candidate `lane` vs kept j in {wv, wv+4, ...}.
            bool sup_part = false;
            for (int j = wv; j < kept; j += 4) {
                float4 kb = kbox[j];
                float ih = fminf(kb.z, mb.z) - fmaxf(kb.x, mb.x); ih = fmaxf(ih, 0.0f);
                float iw = fminf(kb.w, mb.w) - fmaxf(kb.y, mb.y); iw = fmaxf(iw, 0.0f);
                float inter = ih * iw;
                float uni = karea[j] + ma - inter;       // ref op order
                sup_part = sup_part || ((inter / uni) > 0.5f);
            }
            unsigned long long sb = __ballot(sup_part);
            if (lane == 0) supp[wv] = sb;
            __syncthreads();
            unsigned long long m = vb & ~(supp[0] | supp[1] | supp[2] | supp[3]);
            bool doM = (m != 0ull);                      // uniform across all threads
            // Phase 2 (all waves): row chunk for candidate `lane`, cols [16wv,16wv+16).
            if (doM) {
                unsigned long long chunk = 0ull;
#pragma unroll
                for (int jj = 0; jj < 16; ++jj) {
                    int j = (wv << 4) + jj;
                    unsigned long long kj = keys[base + j];        // uniform LDS read
                    unsigned int oj = 0xFFFFFFFFu - (unsigned int)kj;
                    float4 bj = sbox[oj];
                    float aj = sarea[oj];
                    float ih = fminf(bj.z, mb.z) - fmaxf(bj.x, mb.x); ih = fmaxf(ih, 0.0f);
                    float iw = fminf(bj.w, mb.w) - fmaxf(bj.y, mb.y); iw = fmaxf(iw, 0.0f);
                    float inter = ih * iw;
                    float uni = aj + ma - inter;
                    if ((inter / uni) > 0.5f) chunk |= 1ull << jj;
                }
                wmp[wv][lane] = chunk << (wv << 4);
            }
            __syncthreads();
            // Phase 3 (wave 0 only): serial resolution + parallel append.
            if (doM && tid < 64) {
                unsigned long long row = wmp[0][lane] | wmp[1][lane] | wmp[2][lane] | wmp[3][lane];
                unsigned long long Km = 0ull;
                int kept0 = kept;
                while (m != 0ull && kept < MAX_OUT) {
                    int f = __builtin_ctzll(m);
                    Km |= 1ull << f;
                    ++kept;
                    unsigned int rlo = (unsigned int)__builtin_amdgcn_readlane((int)(unsigned int)row, f);
                    unsigned int rhi = (unsigned int)__builtin_amdgcn_readlane((int)(unsigned int)(row >> 32), f);
                    unsigned long long rowf = ((unsigned long long)rhi << 32) | rlo;
                    m &= ~rowf;                          // clears f (self-bit) + suppressed
                }
                if ((Km >> lane) & 1ull) {
                    int pos = kept0 + __popcll(Km & ((1ull << lane) - 1ull));
                    outc[pos] = (int)o;
                    kbox[pos] = mb;
                    karea[pos] = ma;
                }
                if (lane == 0) keptLDS = kept;
            }
            __syncthreads();  // kept/kbox/karea visible to all waves
            kept = keptLDS;
        }
    }

    // --- Publish + last-finisher election (no polling) ---
    // Release store orders wave-0's keptIdx writes (same wave, program order) before
    // the count publish; acq_rel fetch_add gives a total order on `ready` — the block
    // observing prev == poison+79 knows all 80 publishes (and their counts) precede it.
    if (tid == 0) {
        __hip_atomic_store(&counts[c], (unsigned int)kept,
                           __ATOMIC_RELEASE, __HIP_MEMORY_SCOPE_SYSTEM);
        unsigned int prev = __hip_atomic_fetch_add(ready, 1u,
                                                   __ATOMIC_ACQ_REL, __HIP_MEMORY_SCOPE_SYSTEM);
        lastFlag = (prev == WS_POISON + (unsigned int)NUM_CLASSES - 1u) ? 1 : 0;
    }
    __syncthreads();
    if (lastFlag == 0) return;   // 79 blocks exit; the last finisher compacts

    // --- Epilogue (last finisher): gather counts, scan, scatter, tail-zero ---
    if (tid < NUM_CLASSES)
        scnt[tid] = (int)__hip_atomic_load(&counts[tid], __ATOMIC_RELAXED,
                                           __HIP_MEMORY_SCOPE_SYSTEM);
    __syncthreads();

    // Inclusive Hillis-Steele scan over 80 counts in LDS.
    for (int d = 1; d < NUM_CLASSES; d <<= 1) {
        int v = 0;
        if (tid < NUM_CLASSES) {
            v = scnt[tid];
            if (tid >= d) v += scnt[tid - d];
        }
        __syncthreads();
        if (tid < NUM_CLASSES) scnt[tid] = v;
        __syncthreads();
    }

    // Scatter rows (0, c, idx) packed by (class, rank): covers out[0 .. 3*total).
    for (int idx = tid; idx < NUM_CLASSES * MAX_OUT; idx += 256) {
        int c2 = idx / MAX_OUT;
        int r = idx - c2 * MAX_OUT;
        int excl = (c2 == 0) ? 0 : scnt[c2 - 1];
        if (r < scnt[c2] - excl) {
            int o = excl + r;
            out[o * 3 + 0] = 0;  // B == 1
            out[o * 3 + 1] = c2;
            out[o * 3 + 2] = keptIdx[c2 * KEPT_STRIDE + r];
        }
    }
    // Zero only the tail the scatter didn't write (usually empty: total == 8000).
    int total = scnt[NUM_CLASSES - 1];
    for (int i = 3 * total + tid; i < NUM_CLASSES * MAX_OUT * 3; i += 256)
        out[i] = 0;
}

extern "C" void kernel_launch(void* const* d_in, const int* in_sizes, int n_in,
                              void* d_out, int out_size, void* d_ws, size_t ws_size,
                              hipStream_t stream) {
    const float* boxes = (const float*)d_in[0];   // (1, 1024, 4) f32
    const float* scores = (const float*)d_in[1];  // (1, 80, 1024) f32
    int* out = (int*)d_out;                        // (8000, 3) int32

    int* keptIdx = (int*)d_ws;                                     // 80*128 ints
    unsigned int* counts = (unsigned int*)(keptIdx + NUM_CLASSES * KEPT_STRIDE);
    unsigned int* ready = counts + 128;            // own 512B-aligned region

    nms_fused<<<NUM_CLASSES, 256, 0, stream>>>(boxes, scores, keptIdx, counts, ready, out);
}